// Round 1
// baseline (135.784 us; speedup 1.0000x reference)
//
#include <hip/hip_runtime.h>

#define NB 256        // batch N
#define IN_F 1024     // in_features
#define BEX 256       // B_extra
#define KD 16         // intermediate K
#define NJ (BEX * KD) // 4096 GEMM columns
#define OUT_F 1280

// ---------------- kernel A: out[:, :1024] = x ----------------
__global__ __launch_bounds__(256) void k_copy_x(const float* __restrict__ x,
                                                float* __restrict__ out) {
    int idx = blockIdx.x * 256 + threadIdx.x;   // 65536 threads, one float4 each
    int row = idx >> 8;
    int c4  = (idx & 255) << 2;
    *(float4*)(out + row * OUT_F + c4) = *(const float4*)(x + row * IN_F + c4);
}

// ---------------- kernel B: M2[b][n][k] = sum_i x[n][i] * T[i][b*16+k] ----------------
// A = x (256 x 1024), B = T viewed as (1024 x 4096). Tile BM=64, BN=64, BK=16.
// 256 threads = 16x16, each computes a 4x4 micro-tile.
// As stored transposed [k][m] with pad 68 so inner-loop A reads are broadcast float4.
__global__ __launch_bounds__(256) void k_gemm(const float* __restrict__ A,
                                              const float* __restrict__ B,
                                              float* __restrict__ M2) {
    __shared__ float As[16][68];
    __shared__ float Bs[16][68];

    const int t  = threadIdx.x;
    const int tx = t & 15, ty = t >> 4;
    const int m0 = blockIdx.y * 64;
    const int j0 = blockIdx.x * 64;

    // staging assignments
    const int ar = t >> 2;           // 0..63  (m within tile)
    const int ac = (t & 3) << 2;     // 0,4,8,12 (k within tile)
    const int br = t >> 4;           // 0..15  (k within tile)
    const int bc = (t & 15) << 2;    // 0..60  (j within tile)

    const float* Aptr = A + (m0 + ar) * IN_F + ac;   // advance by +k0
    const float* Bptr = B + br * NJ + j0 + bc;       // advance by +k0*NJ

    float4 a_pre = *(const float4*)(Aptr);
    float4 b_pre = *(const float4*)(Bptr);

    float acc[4][4] = {};

    for (int k0 = 0; k0 < IN_F; k0 += 16) {
        // store prefetched tile to LDS
        As[ac + 0][ar] = a_pre.x;
        As[ac + 1][ar] = a_pre.y;
        As[ac + 2][ar] = a_pre.z;
        As[ac + 3][ar] = a_pre.w;
        *(float4*)&Bs[br][bc] = b_pre;
        __syncthreads();

        // prefetch next tile (global latency overlaps compute below)
        if (k0 + 16 < IN_F) {
            a_pre = *(const float4*)(Aptr + (k0 + 16));
            b_pre = *(const float4*)(Bptr + (size_t)(k0 + 16) * NJ);
        }

        #pragma unroll
        for (int kk = 0; kk < 16; ++kk) {
            float4 a = *(const float4*)&As[kk][ty << 2];   // broadcast across tx
            float4 b = *(const float4*)&Bs[kk][tx << 2];
            acc[0][0] += a.x * b.x; acc[0][1] += a.x * b.y; acc[0][2] += a.x * b.z; acc[0][3] += a.x * b.w;
            acc[1][0] += a.y * b.x; acc[1][1] += a.y * b.y; acc[1][2] += a.y * b.z; acc[1][3] += a.y * b.w;
            acc[2][0] += a.z * b.x; acc[2][1] += a.z * b.y; acc[2][2] += a.z * b.z; acc[2][3] += a.z * b.w;
            acc[3][0] += a.w * b.x; acc[3][1] += a.w * b.y; acc[3][2] += a.w * b.z; acc[3][3] += a.w * b.w;
        }
        __syncthreads();
    }

    // write C in (b, n, k) layout: j = b*16 + k; tx*4 stays within one b-group of 16
    const int j    = j0 + (tx << 2);
    const int bidx = j >> 4;
    const int k4   = j & 15;
    float* Cbase = M2 + (size_t)bidx * (NB * KD) + k4;
    #pragma unroll
    for (int im = 0; im < 4; ++im) {
        int m = m0 + (ty << 2) + im;
        *(float4*)(Cbase + m * KD) =
            make_float4(acc[im][0], acc[im][1], acc[im][2], acc[im][3]);
    }
}

// ---------------- kernel C: out[n, 1024+b] = sum_m exp(-L1(M[n,b,:], M[m,b,:])) - 1 ----------------
// one block per b; M2[b] is 256x16 contiguous (16 KB) -> LDS
__global__ __launch_bounds__(256) void k_pairwise(const float* __restrict__ M2,
                                                  float* __restrict__ out) {
    __shared__ float lds[NB * KD];   // 16 KB
    const int b = blockIdx.x;
    const int t = threadIdx.x;
    const float* Mb = M2 + (size_t)b * (NB * KD);

    #pragma unroll
    for (int c = 0; c < 4; ++c)
        *(float4*)&lds[c * 1024 + (t << 2)] = *(const float4*)(Mb + c * 1024 + (t << 2));
    __syncthreads();

    // own row in registers
    float4 q0 = *(const float4*)&lds[t * KD + 0];
    float4 q1 = *(const float4*)&lds[t * KD + 4];
    float4 q2 = *(const float4*)&lds[t * KD + 8];
    float4 q3 = *(const float4*)&lds[t * KD + 12];

    float acc0 = 0.f, acc1 = 0.f;
    for (int m = 0; m < NB; m += 2) {
        const float* r = &lds[m * KD];
        float4 p0 = *(const float4*)(r + 0);
        float4 p1 = *(const float4*)(r + 4);
        float4 p2 = *(const float4*)(r + 8);
        float4 p3 = *(const float4*)(r + 12);
        float4 u0 = *(const float4*)(r + 16);
        float4 u1 = *(const float4*)(r + 20);
        float4 u2 = *(const float4*)(r + 24);
        float4 u3 = *(const float4*)(r + 28);

        float sA = fabsf(q0.x - p0.x) + fabsf(q0.y - p0.y) + fabsf(q0.z - p0.z) + fabsf(q0.w - p0.w)
                 + fabsf(q1.x - p1.x) + fabsf(q1.y - p1.y) + fabsf(q1.z - p1.z) + fabsf(q1.w - p1.w);
        float sB = fabsf(q2.x - p2.x) + fabsf(q2.y - p2.y) + fabsf(q2.z - p2.z) + fabsf(q2.w - p2.w)
                 + fabsf(q3.x - p3.x) + fabsf(q3.y - p3.y) + fabsf(q3.z - p3.z) + fabsf(q3.w - p3.w);
        float sC = fabsf(q0.x - u0.x) + fabsf(q0.y - u0.y) + fabsf(q0.z - u0.z) + fabsf(q0.w - u0.w)
                 + fabsf(q1.x - u1.x) + fabsf(q1.y - u1.y) + fabsf(q1.z - u1.z) + fabsf(q1.w - u1.w);
        float sD = fabsf(q2.x - u2.x) + fabsf(q2.y - u2.y) + fabsf(q2.z - u2.z) + fabsf(q2.w - u2.w)
                 + fabsf(q3.x - u3.x) + fabsf(q3.y - u3.y) + fabsf(q3.z - u3.z) + fabsf(q3.w - u3.w);

        acc0 += __expf(-(sA + sB));
        acc1 += __expf(-(sC + sD));
    }
    // self term contributes exp(0) = 1; reference subtracts it
    out[t * OUT_F + IN_F + b] = acc0 + acc1 - 1.0f;
}

extern "C" void kernel_launch(void* const* d_in, const int* in_sizes, int n_in,
                              void* d_out, int out_size, void* d_ws, size_t ws_size,
                              hipStream_t stream) {
    const float* x = (const float*)d_in[0];   // (256, 1024)
    const float* T = (const float*)d_in[1];   // (1024, 256, 16)
    float* out = (float*)d_out;               // (256, 1280)
    float* M2  = (float*)d_ws;                // (256 b, 256 n, 16 k) = 4 MB

    k_copy_x<<<dim3(256), dim3(256), 0, stream>>>(x, out);
    k_gemm<<<dim3(64, 4), dim3(256), 0, stream>>>(x, T, M2);
    k_pairwise<<<dim3(256), dim3(256), 0, stream>>>(M2, out);
}

// Round 2
// 103.472 us; speedup vs baseline: 1.3123x; 1.3123x over previous
//
#include <hip/hip_runtime.h>
#include <hip/hip_fp16.h>
#include <hip/hip_bf16.h>

#define NB 256
#define IN_F 1024
#define BEX 256
#define KD 16
#define NJ 4096
#define OUT_F 1280

typedef short bf16x8 __attribute__((ext_vector_type(8)));
typedef float f32x4 __attribute__((ext_vector_type(4)));

__device__ inline unsigned short f2bf(float f) {
    __hip_bfloat16 h = __float2bfloat16(f);
    return *reinterpret_cast<unsigned short*>(&h);
}

__device__ inline void cp16(const void* g, void* l) {
    __builtin_amdgcn_global_load_lds((const __attribute__((address_space(1))) void*)g,
                                     (__attribute__((address_space(3))) void*)l, 16, 0, 0);
}

// ---- kernel A: out[:, :1024] = x ; x_bf = bf16(x) ; out[:, 1024:] = -1 ----
__global__ __launch_bounds__(256) void k_copy_x(const float* __restrict__ x,
                                                float* __restrict__ out,
                                                unsigned short* __restrict__ x_bf) {
    const int r = blockIdx.x;
    const int t = threadIdx.x;
    float4 v = *(const float4*)(x + (size_t)r * IN_F + t * 4);
    *(float4*)(out + (size_t)r * OUT_F + t * 4) = v;
    ushort4 o;
    o.x = f2bf(v.x); o.y = f2bf(v.y); o.z = f2bf(v.z); o.w = f2bf(v.w);
    *(ushort4*)(x_bf + (size_t)r * IN_F + t * 4) = o;
    if (t < 64)
        *(float4*)(out + (size_t)r * OUT_F + IN_F + t * 4) = make_float4(-1.f, -1.f, -1.f, -1.f);
}

// ---- kernel B: Tt[j][i] = bf16(T[i][j])  (1024x4096 fp32 -> 4096x1024 bf16) ----
__global__ __launch_bounds__(256) void k_transpose(const float* __restrict__ T,
                                                   unsigned short* __restrict__ Tt) {
    __shared__ float tile[32][33];
    const int i0 = blockIdx.y * 32;
    const int j0 = blockIdx.x * 32;
    const int t = threadIdx.x;
    {
        const int r = t >> 3, cg = (t & 7) << 2;
        float4 v = *(const float4*)(T + (size_t)(i0 + r) * NJ + j0 + cg);
        tile[r][cg + 0] = v.x; tile[r][cg + 1] = v.y;
        tile[r][cg + 2] = v.z; tile[r][cg + 3] = v.w;
    }
    __syncthreads();
    const int jr = t >> 3, ig = (t & 7) << 2;
    ushort4 o;
    o.x = f2bf(tile[ig + 0][jr]);
    o.y = f2bf(tile[ig + 1][jr]);
    o.z = f2bf(tile[ig + 2][jr]);
    o.w = f2bf(tile[ig + 3][jr]);
    *(ushort4*)(Tt + (size_t)(j0 + jr) * IN_F + i0 + ig) = o;
}

// ---- kernel C: bf16 MFMA GEMM: C[n][j] = sum_i x_bf[n][i] * Tt[j][i], C -> fp16 M2h[b][n][k] ----
// 64x64 tile per block, 4 waves each 32x32 (2x2 MFMA tiles), BK=128, double-buffered DMA.
// LDS swizzle: element (row, kg(0..15), e(0..7)) at row*128 + (kg ^ (row&15))*8 + e  (DMA-contiguous, 2-way reads)
__global__ __launch_bounds__(256) void k_gemm(const unsigned short* __restrict__ A,   // [256][1024]
                                              const unsigned short* __restrict__ B,   // [4096][1024]
                                              __half* __restrict__ M2h) {
    __shared__ unsigned short lds[4][64 * 128];   // [buf*2 + (A=0,B=1)]  64 KB
    const int t = threadIdx.x;
    const int w = t >> 6, l = t & 63;
    const int n0 = blockIdx.y * 64;
    const int j0 = blockIdx.x * 64;

    // DMA source precompute: slots s = t + p*256
    const unsigned short* aA[4];
    const unsigned short* aB[4];
    int lofs[4];
    #pragma unroll
    for (int p = 0; p < 4; ++p) {
        int s = t + p * 256;
        int r = s >> 4;
        int kg = (s & 15) ^ (r & 15);
        aA[p] = A + (size_t)(n0 + r) * IN_F + kg * 8;
        aB[p] = B + (size_t)(j0 + r) * IN_F + kg * 8;
        lofs[p] = s * 8;   // ushort units (16 B per slot)
    }

    f32x4 acc[2][2];
    #pragma unroll
    for (int i = 0; i < 2; ++i)
        #pragma unroll
        for (int j = 0; j < 2; ++j)
            acc[i][j] = (f32x4){0.f, 0.f, 0.f, 0.f};

    // stage k-chunk 0 into buf 0
    #pragma unroll
    for (int p = 0; p < 4; ++p) cp16(aA[p], &lds[0][lofs[p]]);
    #pragma unroll
    for (int p = 0; p < 4; ++p) cp16(aB[p], &lds[1][lofs[p]]);

    const int rowA0 = ((w & 1) * 32 + (l & 15)) * 128;
    const int rowA1 = rowA0 + 16 * 128;
    const int rowB0 = (((w >> 1) & 1) * 32 + (l & 15)) * 128;
    const int rowB1 = rowB0 + 16 * 128;

    for (int s = 0; s < 8; ++s) {
        __syncthreads();   // drains DMA(s); readers of buf s-1 are done
        if (s < 7) {
            const int k0 = (s + 1) * 128;
            const int bsel = ((s + 1) & 1) * 2;
            #pragma unroll
            for (int p = 0; p < 4; ++p) cp16(aA[p] + k0, &lds[bsel + 0][lofs[p]]);
            #pragma unroll
            for (int p = 0; p < 4; ++p) cp16(aB[p] + k0, &lds[bsel + 1][lofs[p]]);
        }
        const unsigned short* La = lds[(s & 1) * 2 + 0];
        const unsigned short* Lb = lds[(s & 1) * 2 + 1];
        #pragma unroll
        for (int kk = 0; kk < 4; ++kk) {
            const int kg = kk * 4 + (l >> 4);
            const int ks = (kg ^ (l & 15)) * 8;
            bf16x8 a0 = *(const bf16x8*)&La[rowA0 + ks];
            bf16x8 a1 = *(const bf16x8*)&La[rowA1 + ks];
            bf16x8 b0 = *(const bf16x8*)&Lb[rowB0 + ks];
            bf16x8 b1 = *(const bf16x8*)&Lb[rowB1 + ks];
            acc[0][0] = __builtin_amdgcn_mfma_f32_16x16x32_bf16(a0, b0, acc[0][0], 0, 0, 0);
            acc[0][1] = __builtin_amdgcn_mfma_f32_16x16x32_bf16(a0, b1, acc[0][1], 0, 0, 0);
            acc[1][0] = __builtin_amdgcn_mfma_f32_16x16x32_bf16(a1, b0, acc[1][0], 0, 0, 0);
            acc[1][1] = __builtin_amdgcn_mfma_f32_16x16x32_bf16(a1, b1, acc[1][1], 0, 0, 0);
        }
    }

    // epilogue: D layout col = l&15, row = (l>>4)*4 + reg  ->  M2h[b][n][k]
    const int col = l & 15;
    #pragma unroll
    for (int nt = 0; nt < 2; ++nt) {
        #pragma unroll
        for (int jt = 0; jt < 2; ++jt) {
            const int jc = j0 + ((w >> 1) & 1) * 32 + jt * 16 + col;
            const int b = jc >> 4;
            const int k = jc & 15;
            __half* base = M2h + (size_t)b * (NB * KD) + k;
            #pragma unroll
            for (int r = 0; r < 4; ++r) {
                const int n = n0 + (w & 1) * 32 + nt * 16 + (l >> 4) * 4 + r;
                base[n * KD] = __float2half(acc[nt][jt][r]);
            }
        }
    }
}

// ---- kernel D: pairwise L1 + exp, packed fp16, atomicAdd partials ----
// grid (128 bpairs, 4 mchunks); block 256: waves 0-1 -> b0, waves 2-3 -> b1; each thread 2 q-rows
__global__ __launch_bounds__(256) void k_pairwise(const __half* __restrict__ M2h,
                                                  float* __restrict__ out) {
    __shared__ __half lds[2][64][16];   // 4 KB: chunk rows for b0, b1
    const int bpair = blockIdx.x;
    const int mc = blockIdx.y;
    const int t = threadIdx.x;
    const int half = t >> 7;
    const int b = bpair * 2 + half;
    const int tl = t & 127;

    {   // stage chunk (64 rows x 16 halfs x 2 b's) = 4 KB, one 16B slot per thread
        const int bb = t >> 7, idx = t & 127, row = idx >> 1, h = idx & 1;
        float4 v = *(const float4*)(M2h + (size_t)(bpair * 2 + bb) * (NB * KD)
                                    + (mc * 64 + row) * KD + h * 8);
        *(float4*)&lds[bb][row][h * 8] = v;
    }

    union U { float4 f; __half2 h[4]; };
    U q0a, q0b, q1a, q1b;
    {
        const __half* q0p = M2h + (size_t)b * (NB * KD) + tl * KD;
        const __half* q1p = M2h + (size_t)b * (NB * KD) + (tl + 128) * KD;
        q0a.f = *(const float4*)(q0p);     q0b.f = *(const float4*)(q0p + 8);
        q1a.f = *(const float4*)(q1p);     q1b.f = *(const float4*)(q1p + 8);
    }
    __syncthreads();

    float e0 = 0.f, e1 = 0.f;
    #pragma unroll 2
    for (int m = 0; m < 64; ++m) {
        U pa, pb;
        pa.f = *(const float4*)&lds[half][m][0];
        pb.f = *(const float4*)&lds[half][m][8];

        // q0 vs p
        {
            __half2 s0 = __hadd2(__habs2(__hsub2(q0a.h[0], pa.h[0])), __habs2(__hsub2(q0a.h[1], pa.h[1])));
            __half2 s1 = __hadd2(__habs2(__hsub2(q0a.h[2], pa.h[2])), __habs2(__hsub2(q0a.h[3], pa.h[3])));
            __half2 s2 = __hadd2(__habs2(__hsub2(q0b.h[0], pb.h[0])), __habs2(__hsub2(q0b.h[1], pb.h[1])));
            __half2 s3 = __hadd2(__habs2(__hsub2(q0b.h[2], pb.h[2])), __habs2(__hsub2(q0b.h[3], pb.h[3])));
            __half2 sA = __hadd2(s0, s1);
            __half2 sB = __hadd2(s2, s3);
            float2 fa = __half22float2(sA);
            float2 fb = __half22float2(sB);
            float l1 = (fa.x + fa.y) + (fb.x + fb.y);
            e0 += __expf(-l1);
        }
        // q1 vs p
        {
            __half2 s0 = __hadd2(__habs2(__hsub2(q1a.h[0], pa.h[0])), __habs2(__hsub2(q1a.h[1], pa.h[1])));
            __half2 s1 = __hadd2(__habs2(__hsub2(q1a.h[2], pa.h[2])), __habs2(__hsub2(q1a.h[3], pa.h[3])));
            __half2 s2 = __hadd2(__habs2(__hsub2(q1b.h[0], pb.h[0])), __habs2(__hsub2(q1b.h[1], pb.h[1])));
            __half2 s3 = __hadd2(__habs2(__hsub2(q1b.h[2], pb.h[2])), __habs2(__hsub2(q1b.h[3], pb.h[3])));
            __half2 sA = __hadd2(s0, s1);
            __half2 sB = __hadd2(s2, s3);
            float2 fa = __half22float2(sA);
            float2 fb = __half22float2(sB);
            float l1 = (fa.x + fa.y) + (fb.x + fb.y);
            e1 += __expf(-l1);
        }
    }
    atomicAdd(&out[(size_t)tl * OUT_F + IN_F + b], e0);
    atomicAdd(&out[(size_t)(tl + 128) * OUT_F + IN_F + b], e1);
}

extern "C" void kernel_launch(void* const* d_in, const int* in_sizes, int n_in,
                              void* d_out, int out_size, void* d_ws, size_t ws_size,
                              hipStream_t stream) {
    const float* x = (const float*)d_in[0];   // (256, 1024)
    const float* T = (const float*)d_in[1];   // (1024, 256, 16) == (1024, 4096)
    float* out = (float*)d_out;               // (256, 1280)

    char* ws = (char*)d_ws;
    unsigned short* x_bf = (unsigned short*)ws;                        // 512 KB
    unsigned short* Tt   = (unsigned short*)(ws + (1u << 19));         // 8 MB
    __half* M2h          = (__half*)(ws + (1u << 19) + (1u << 23));    // 2 MB

    k_copy_x<<<dim3(256), dim3(256), 0, stream>>>(x, out, x_bf);
    k_transpose<<<dim3(128, 32), dim3(256), 0, stream>>>(T, Tt);
    k_gemm<<<dim3(64, 4), dim3(256), 0, stream>>>(x_bf, Tt, M2h);
    k_pairwise<<<dim3(128, 4), dim3(256), 0, stream>>>(M2h, out);
}

// Round 3
// 96.360 us; speedup vs baseline: 1.4091x; 1.0738x over previous
//
#include <hip/hip_runtime.h>
#include <hip/hip_fp16.h>
#include <hip/hip_bf16.h>

#define NB 256
#define IN_F 1024
#define BEX 256
#define KD 16
#define NJ 4096
#define OUT_F 1280

typedef short bf16x8 __attribute__((ext_vector_type(8)));
typedef float f32x4 __attribute__((ext_vector_type(4)));
typedef _Float16 h2 __attribute__((ext_vector_type(2)));

__device__ inline unsigned short f2bf(float f) {
    __hip_bfloat16 h = __float2bfloat16(f);
    return *reinterpret_cast<unsigned short*>(&h);
}

__device__ inline void cp16(const void* g, void* l) {
    __builtin_amdgcn_global_load_lds((const __attribute__((address_space(1))) void*)g,
                                     (__attribute__((address_space(3))) void*)l, 16, 0, 0);
}

// ---- kernel 1: prep = transpose/convert T  +  copy x / bf16(x) / out-init ----
// blocks [0, 4096): transpose 32x32 tile of T (1024x4096 f32) -> Tt (4096x1024 bf16)
// blocks [4096, 4352): row r = bid-4096: out[r,:1024]=x[r], x_bf[r]=bf16(x[r]), out[r,1024:]=-1
__global__ __launch_bounds__(256) void k_prep(const float* __restrict__ x,
                                              const float* __restrict__ T,
                                              float* __restrict__ out,
                                              unsigned short* __restrict__ x_bf,
                                              unsigned short* __restrict__ Tt) {
    const int bid = blockIdx.x;
    const int t = threadIdx.x;
    if (bid < 4096) {
        __shared__ float tile[32][33];
        const int j0 = (bid & 127) * 32;
        const int i0 = (bid >> 7) * 32;
        {
            const int r = t >> 3, cg = (t & 7) << 2;
            float4 v = *(const float4*)(T + (size_t)(i0 + r) * NJ + j0 + cg);
            tile[r][cg + 0] = v.x; tile[r][cg + 1] = v.y;
            tile[r][cg + 2] = v.z; tile[r][cg + 3] = v.w;
        }
        __syncthreads();
        const int jr = t >> 3, ig = (t & 7) << 2;
        ushort4 o;
        o.x = f2bf(tile[ig + 0][jr]);
        o.y = f2bf(tile[ig + 1][jr]);
        o.z = f2bf(tile[ig + 2][jr]);
        o.w = f2bf(tile[ig + 3][jr]);
        *(ushort4*)(Tt + (size_t)(j0 + jr) * IN_F + i0 + ig) = o;
    } else {
        const int r = bid - 4096;
        float4 v = *(const float4*)(x + (size_t)r * IN_F + t * 4);
        *(float4*)(out + (size_t)r * OUT_F + t * 4) = v;
        ushort4 o;
        o.x = f2bf(v.x); o.y = f2bf(v.y); o.z = f2bf(v.z); o.w = f2bf(v.w);
        *(ushort4*)(x_bf + (size_t)r * IN_F + t * 4) = o;
        if (t < 64)
            *(float4*)(out + (size_t)r * OUT_F + IN_F + t * 4) =
                make_float4(-1.f, -1.f, -1.f, -1.f);
    }
}

// ---- kernel 2: bf16 MFMA GEMM (unchanged from R2): M2h[b][n][k] fp16 ----
__global__ __launch_bounds__(256) void k_gemm(const unsigned short* __restrict__ A,   // [256][1024]
                                              const unsigned short* __restrict__ B,   // [4096][1024]
                                              __half* __restrict__ M2h) {
    __shared__ unsigned short lds[4][64 * 128];   // 64 KB
    const int t = threadIdx.x;
    const int w = t >> 6, l = t & 63;
    const int n0 = blockIdx.y * 64;
    const int j0 = blockIdx.x * 64;

    const unsigned short* aA[4];
    const unsigned short* aB[4];
    int lofs[4];
    #pragma unroll
    for (int p = 0; p < 4; ++p) {
        int s = t + p * 256;
        int r = s >> 4;
        int kg = (s & 15) ^ (r & 15);
        aA[p] = A + (size_t)(n0 + r) * IN_F + kg * 8;
        aB[p] = B + (size_t)(j0 + r) * IN_F + kg * 8;
        lofs[p] = s * 8;
    }

    f32x4 acc[2][2];
    #pragma unroll
    for (int i = 0; i < 2; ++i)
        #pragma unroll
        for (int j = 0; j < 2; ++j)
            acc[i][j] = (f32x4){0.f, 0.f, 0.f, 0.f};

    #pragma unroll
    for (int p = 0; p < 4; ++p) cp16(aA[p], &lds[0][lofs[p]]);
    #pragma unroll
    for (int p = 0; p < 4; ++p) cp16(aB[p], &lds[1][lofs[p]]);

    const int rowA0 = ((w & 1) * 32 + (l & 15)) * 128;
    const int rowA1 = rowA0 + 16 * 128;
    const int rowB0 = (((w >> 1) & 1) * 32 + (l & 15)) * 128;
    const int rowB1 = rowB0 + 16 * 128;

    for (int s = 0; s < 8; ++s) {
        __syncthreads();
        if (s < 7) {
            const int k0 = (s + 1) * 128;
            const int bsel = ((s + 1) & 1) * 2;
            #pragma unroll
            for (int p = 0; p < 4; ++p) cp16(aA[p] + k0, &lds[bsel + 0][lofs[p]]);
            #pragma unroll
            for (int p = 0; p < 4; ++p) cp16(aB[p] + k0, &lds[bsel + 1][lofs[p]]);
        }
        const unsigned short* La = lds[(s & 1) * 2 + 0];
        const unsigned short* Lb = lds[(s & 1) * 2 + 1];
        #pragma unroll
        for (int kk = 0; kk < 4; ++kk) {
            const int kg = kk * 4 + (l >> 4);
            const int ks = (kg ^ (l & 15)) * 8;
            bf16x8 a0 = *(const bf16x8*)&La[rowA0 + ks];
            bf16x8 a1 = *(const bf16x8*)&La[rowA1 + ks];
            bf16x8 b0 = *(const bf16x8*)&Lb[rowB0 + ks];
            bf16x8 b1 = *(const bf16x8*)&Lb[rowB1 + ks];
            acc[0][0] = __builtin_amdgcn_mfma_f32_16x16x32_bf16(a0, b0, acc[0][0], 0, 0, 0);
            acc[0][1] = __builtin_amdgcn_mfma_f32_16x16x32_bf16(a0, b1, acc[0][1], 0, 0, 0);
            acc[1][0] = __builtin_amdgcn_mfma_f32_16x16x32_bf16(a1, b0, acc[1][0], 0, 0, 0);
            acc[1][1] = __builtin_amdgcn_mfma_f32_16x16x32_bf16(a1, b1, acc[1][1], 0, 0, 0);
        }
    }

    const int col = l & 15;
    #pragma unroll
    for (int nt = 0; nt < 2; ++nt) {
        #pragma unroll
        for (int jt = 0; jt < 2; ++jt) {
            const int jc = j0 + ((w >> 1) & 1) * 32 + jt * 16 + col;
            const int b = jc >> 4;
            const int k = jc & 15;
            __half* base = M2h + (size_t)b * (NB * KD) + k;
            #pragma unroll
            for (int r = 0; r < 4; ++r) {
                const int n = n0 + (w & 1) * 32 + nt * 16 + (l >> 4) * 4 + r;
                base[n * KD] = __float2half(acc[nt][jt][r]);
            }
        }
    }
}

// ---- kernel 3: pairwise v3 ----
// grid (256 b, 2 mhalf); block 256. Stage 128 m-rows (4 KB). Thread t: qg=t&63 owns
// q-rows qg*4..+3 (regs), ms=t>>6 covers m in [ms*32, +32). fdot2 L1 accumulate,
// in-block reduction over ms, one atomicAdd per (q,b) per block.
union U8 { float4 f4[2]; h2 h[8]; };

__global__ __launch_bounds__(256) void k_pairwise(const __half* __restrict__ M2h,
                                                  float* __restrict__ out) {
    __shared__ __half rows[128 * KD];   // 4 KB
    __shared__ float part[256 * 4];     // 4 KB
    const int b = blockIdx.x;
    const int mh = blockIdx.y;
    const int t = threadIdx.x;
    const int qg = t & 63, ms = t >> 6;
    const __half* Mb = M2h + (size_t)b * (NB * KD);

    ((float4*)rows)[t] = ((const float4*)(Mb + mh * 128 * KD))[t];

    U8 q[4];
    #pragma unroll
    for (int r = 0; r < 4; ++r) {
        const __half* qp = Mb + (qg * 4 + r) * KD;
        q[r].f4[0] = *(const float4*)(qp);
        q[r].f4[1] = *(const float4*)(qp + 8);
    }
    __syncthreads();

    const h2 one = {(_Float16)1.0f, (_Float16)1.0f};
    float e[4] = {0.f, 0.f, 0.f, 0.f};

    #pragma unroll 2
    for (int m = 0; m < 32; ++m) {
        U8 p;
        const __half* rp = rows + (ms * 32 + m) * KD;
        p.f4[0] = *(const float4*)(rp);
        p.f4[1] = *(const float4*)(rp + 8);
        #pragma unroll
        for (int r = 0; r < 4; ++r) {
            float l0 = 0.f, l1 = 0.f;
            #pragma unroll
            for (int i = 0; i < 8; i += 2) {
                h2 d0 = q[r].h[i] - p.h[i];
                h2 d1 = q[r].h[i + 1] - p.h[i + 1];
                unsigned u0 = (*(unsigned*)&d0) & 0x7FFF7FFFu;
                unsigned u1 = (*(unsigned*)&d1) & 0x7FFF7FFFu;
                l0 = __builtin_amdgcn_fdot2(*(h2*)&u0, one, l0, false);
                l1 = __builtin_amdgcn_fdot2(*(h2*)&u1, one, l1, false);
            }
            e[r] += __expf(-(l0 + l1));
        }
    }

    #pragma unroll
    for (int r = 0; r < 4; ++r)
        part[(qg * 4 + r) * 4 + ms] = e[r];
    __syncthreads();

    float4 p4 = ((const float4*)part)[t];
    atomicAdd(&out[(size_t)t * OUT_F + IN_F + b], p4.x + p4.y + p4.z + p4.w);
}

extern "C" void kernel_launch(void* const* d_in, const int* in_sizes, int n_in,
                              void* d_out, int out_size, void* d_ws, size_t ws_size,
                              hipStream_t stream) {
    const float* x = (const float*)d_in[0];   // (256, 1024)
    const float* T = (const float*)d_in[1];   // (1024, 4096)
    float* out = (float*)d_out;               // (256, 1280)

    char* ws = (char*)d_ws;
    unsigned short* x_bf = (unsigned short*)ws;                        // 512 KB
    unsigned short* Tt   = (unsigned short*)(ws + (1u << 19));         // 8 MB
    __half* M2h          = (__half*)(ws + (1u << 19) + (1u << 23));    // 2 MB

    k_prep<<<dim3(4352), dim3(256), 0, stream>>>(x, T, out, x_bf, Tt);
    k_gemm<<<dim3(64, 4), dim3(256), 0, stream>>>(x_bf, Tt, M2h);
    k_pairwise<<<dim3(256, 2), dim3(256), 0, stream>>>(M2h, out);
}